// Round 4
// baseline (323.607 us; speedup 1.0000x reference)
//
#include <hip/hip_runtime.h>
#include <cstdint>
#include <cstddef>

#define F_ALPHA 0.5f
#define THRESH  0.5f
#define EPS8    1e-8f
#define EPS7    1e-7f
#define MAXM    64
#define CCLS    21
#define MCH     10     // ioubuf chunk rows
#define NSCAN   25     // scanners per row in bp reduce
#define NBUCK   1024   // cx sort buckets

// ---------------------------------------------------------------------------
// Sort pipeline: priors sorted by center-x so consecutive blocks are
// spatially local -> block-uniform GT rejection in match_kernel.
// dbox is batch-invariant; sort is redone every call (graph-safe).
// ---------------------------------------------------------------------------
__global__ __launch_bounds__(256)
void histo_kernel(const float4* __restrict__ dbox, int* __restrict__ hist,
                  unsigned long long* __restrict__ bpkey, int P, int nbp)
{
    int i = blockIdx.x * 256 + threadIdx.x;
    if (i < nbp) bpkey[i] = 0x00000000FFFFFFFFull;   // key(iou=0, p=0) fallback
    if (i < P) {
        float4 d = dbox[i];
        float cx = 0.5f * (d.x + d.z);
        int bk = min(max((int)(cx * (float)NBUCK), 0), NBUCK - 1);
        atomicAdd(&hist[bk], 1);
    }
}

__global__ __launch_bounds__(1024)
void scan_kernel(const int* __restrict__ hist, int* __restrict__ offs)
{
    __shared__ int tmp[NBUCK];
    int t = threadIdx.x;
    int h = hist[t];
    int v = h;
    tmp[t] = v;
    __syncthreads();
    for (int d = 1; d < NBUCK; d <<= 1) {
        int u = (t >= d) ? tmp[t - d] : 0;
        __syncthreads();
        v += u;
        tmp[t] = v;
        __syncthreads();
    }
    offs[t] = v - h;    // exclusive prefix
}

__global__ __launch_bounds__(256)
void scatter_kernel(const float4* __restrict__ dbox, int* __restrict__ offs,
                    float4* __restrict__ sbox, int* __restrict__ sperm, int P)
{
    int p = blockIdx.x * 256 + threadIdx.x;
    if (p < P) {
        float4 d = dbox[p];
        float cx = 0.5f * (d.x + d.z);
        int bk = min(max((int)(cx * (float)NBUCK), 0), NBUCK - 1);
        int pos = atomicAdd(&offs[bk], 1);   // within-bucket order arbitrary: result-safe
        sbox[pos] = d;
        sperm[pos] = p;
    }
}

// ---------------------------------------------------------------------------
// Kernel A: matching on sorted priors with block-uniform GT rejection.
// grid = (ceil(P/256), B), block = 256.
// ---------------------------------------------------------------------------
__global__ __launch_bounds__(256)
void match_kernel(const float4* __restrict__ sbox, const int* __restrict__ sperm,
                  const float4* __restrict__ gt,
                  unsigned long long* __restrict__ bpkey,
                  unsigned char* __restrict__ match, int P, int M)
{
    __shared__ float4 tb[MAXM];
    __shared__ float  tarea[MAXM];
    __shared__ float  ioubuf[MCH * 257];
    __shared__ float  pval[MCH * NSCAN];
    __shared__ int    pidx[MCH * NSCAN];
    __shared__ float  redmin[4], redmax[4];
    __shared__ unsigned amask_lo, amask_hi;

    const int t = threadIdx.x;
    const int b = blockIdx.y;
    const int p0 = blockIdx.x * 256;
    const int p = p0 + t;
    const bool valid = (p < P);

    if (t < M) {
        float4 g = gt[(size_t)b * M + t];
        tb[t] = g;
        tarea[t] = (g.z - g.x) * (g.w - g.y);
    }

    float4 d = valid ? sbox[p] : make_float4(2.f, 2.f, 2.f, 2.f);
    const int orig = valid ? sperm[p] : 0;

    // block x-extent over valid lanes
    float sx = valid ? d.x : 1e30f;
    float sz = valid ? d.z : -1e30f;
    for (int o = 32; o > 0; o >>= 1) {
        sx = fminf(sx, __shfl_xor(sx, o, 64));
        sz = fmaxf(sz, __shfl_xor(sz, o, 64));
    }
    const int wv = t >> 6, lane = t & 63;
    if (lane == 0) { redmin[wv] = sx; redmax[wv] = sz; }
    __syncthreads();
    const float bminx = fminf(fminf(redmin[0], redmin[1]), fminf(redmin[2], redmin[3]));
    const float bmaxz = fmaxf(fmaxf(redmax[0], redmax[1]), fmaxf(redmax[2], redmax[3]));

    // active-GT ballot (GT overlaps block x-range); wave 0 holds bits 0..M-1
    bool act = (t < M) && (tb[t].x < bmaxz) && (tb[t].z > bminx);
    unsigned long long bal = __ballot(act);
    if (t == 0) { amask_lo = (unsigned)bal; amask_hi = (unsigned)(bal >> 32); }
    __syncthreads();
    const unsigned long long amask = ((unsigned long long)amask_hi << 32) | amask_lo;

    const float darea = (d.z - d.x) * (d.w - d.y);
    float best = -1.0f;     // strict > => first-index tie (among computed; 0-iou rows harmless)
    int   bm = 0;

    for (int chunk = 0; chunk < M; chunk += MCH) {
        const int rows = min(MCH, M - chunk);
        const unsigned long long cmask =
            (amask >> chunk) & ((rows >= 64) ? ~0ull : ((1ull << rows) - 1ull));
        if (cmask == 0) continue;              // block-uniform: skip chunk + barriers

        for (int r = 0; r < rows; r++) {
            const int m = chunk + r;
            if (!((amask >> m) & 1)) continue; // wave-uniform scalar branch
            float iou;
            if (valid) {
                float4 g = tb[m];
                float lx = fmaxf(d.x, g.x), ly = fmaxf(d.y, g.y);
                float rx = fminf(d.z, g.z), ry = fminf(d.w, g.w);
                float ww = fmaxf(rx - lx, 0.f), hh = fmaxf(ry - ly, 0.f);
                float inter = ww * hh;
                iou = inter * __builtin_amdgcn_rcpf(darea + tarea[m] - inter);
            } else {
                iou = -1.0f;
            }
            ioubuf[r * 257 + t] = iou;
            if (iou > best) { best = iou; bm = m; }
        }
        __syncthreads();
        if (t < rows * NSCAN) {
            const int row = t / NSCAN, s = t % NSCAN;
            float bv = -2.0f; int bj = 0;
            if ((amask >> (chunk + row)) & 1) {       // inactive row = stale LDS, skip
                for (int j = s; j < 256; j += NSCAN) {
                    float v = ioubuf[row * 257 + j];
                    if (v > bv) { bv = v; bj = j; }
                }
            }
            pval[t] = bv; pidx[t] = bj;
        }
        __syncthreads();
        if (t < rows && ((amask >> (chunk + t)) & 1)) {
            float bv = -2.0f; int bj = 1 << 30;
            for (int s = 0; s < NSCAN; s++) {
                float v = pval[t * NSCAN + s]; int j = pidx[t * NSCAN + s];
                if (v > bv || (v == bv && j < bj)) { bv = v; bj = j; }
            }
            if (bv > 0.0f) {
                unsigned pp = (unsigned)sperm[p0 + bj];   // orig index for global tie-break
                unsigned long long key =
                    ((unsigned long long)__float_as_uint(bv) << 32)
                    | (unsigned long long)(0xFFFFFFFFu - pp);
                atomicMax(&bpkey[(size_t)b * M + (chunk + t)], key);
            }
        }
        __syncthreads();
    }

    if (valid) {
        unsigned char code = (unsigned char)((best >= THRESH ? 0x40 : 0) | bm);
        match[(size_t)b * P + orig] = code;
    }
}

// ---------------------------------------------------------------------------
// Kernel B: force-match each GT's best prior (sequential per batch: last-wins
// scatter semantics for duplicate best priors). Tiny.
// ---------------------------------------------------------------------------
__global__ void force_kernel(const unsigned long long* __restrict__ bpkey,
                             unsigned char* __restrict__ match, int P, int M)
{
    int b = blockIdx.x;
    if (threadIdx.x == 0) {
        for (int j = 0; j < M; j++) {
            unsigned p = 0xFFFFFFFFu - (unsigned)(bpkey[(size_t)b * M + j] & 0xFFFFFFFFull);
            match[(size_t)b * P + p] = (unsigned char)(0x80 | j);
        }
    }
}

// ---------------------------------------------------------------------------
// Kernel C: focal loss on every anchor (conf via coalesced LDS staging) +
// GIoU on positives. Per-block partials to private slots (no atomics).
// ---------------------------------------------------------------------------
__global__ __launch_bounds__(256)
void loss_kernel(const float4* __restrict__ locp,
                 const float*  __restrict__ conf,
                 const float4* __restrict__ dbox,
                 const float4* __restrict__ gt,
                 const int*    __restrict__ gtl,
                 const unsigned char* __restrict__ match,
                 double* __restrict__ partS,
                 int*    __restrict__ partC,
                 int P, int M)
{
    __shared__ float    scf[256 * CCLS];
    __shared__ float4   tb[MAXM];
    __shared__ int      tl[MAXM];
    __shared__ double   sv[4];
    __shared__ int      sc[4];

    const int t = threadIdx.x;
    const int b = blockIdx.y;
    const int p0 = blockIdx.x * 256;
    const int p = p0 + t;

    if (t < M) {
        tb[t] = gt[(size_t)b * M + t];
        tl[t] = gtl[(size_t)b * M + t];
    }

    const int cnt = min(256, P - p0);
    const int nf = cnt * CCLS;
    const float* src = conf + ((size_t)b * P + p0) * CCLS;
    {
        const int n4 = nf >> 2;
        const float4* s4 = (const float4*)src;   // base always 16B-aligned here
        float4* d4 = (float4*)scf;
        for (int i = t; i < n4; i += 256) d4[i] = s4[i];
        for (int i = (n4 << 2) + t; i < nf; i += 256) scf[i] = src[i];
    }
    __syncthreads();

    double acc = 0.0;
    int cnt_pos = 0;
    if (p < P) {
        unsigned char code = match[(size_t)b * P + p];
        int  idx = code & 0x3F;
        bool pos = (code & 0xC0) != 0;
        int  lbl = pos ? tl[idx] : 0;

        const float* x = scf + t * CCLS;
        float mx = -1e30f;
        #pragma unroll
        for (int c = 0; c < CCLS; c++) mx = fmaxf(mx, x[c]);
        float sum = 0.f;
        #pragma unroll
        for (int c = 0; c < CCLS; c++) sum += expf(x[c] - mx);
        float ce = (mx + logf(sum)) - x[lbl];
        float pt = expf(-ce);
        float om = 1.f - pt;
        acc = (double)(F_ALPHA * om * sqrtf(om) * ce);

        if (pos) {
            cnt_pos = 1;
            float4 d = dbox[p];
            float dw = d.z - d.x, dh = d.w - d.y;
            float dcx = d.x + dw * 0.5f, dcy = d.y + dh * 0.5f;
            float4 g = tb[idx];
            float gw = g.z - g.x, gh = g.w - g.y;
            float gcx = g.x + gw * 0.5f, gcy = g.y + gh * 0.5f;
            float ex = (gcx - dcx) / (dw + EPS8);
            float ey = (gcy - dcy) / (dh + EPS8);
            float ew = logf(gw / (dw + EPS8) + EPS8);
            float eh = logf(gh / (dh + EPS8) + EPS8);
            float tcx = ex * dw + dcx, tcy = ey * dh + dcy;
            float tw = expf(ew) * dw,  th = expf(eh) * dh;
            float t0 = tcx - tw * 0.5f, t1 = tcy - th * 0.5f;
            float t2 = tcx + tw * 0.5f, t3 = tcy + th * 0.5f;
            float4 l = locp[(size_t)b * P + p];
            float pcx = l.x * dw + dcx, pcy = l.y * dh + dcy;
            float pw = expf(l.z) * dw,  ph = expf(l.w) * dh;
            float q0 = pcx - pw * 0.5f, q1 = pcy - ph * 0.5f;
            float q2 = pcx + pw * 0.5f, q3 = pcy + ph * 0.5f;
            float ix0 = fmaxf(q0, t0), iy0 = fmaxf(q1, t1);
            float ix1 = fminf(q2, t2), iy1 = fminf(q3, t3);
            float iw = fmaxf(ix1 - ix0, 0.f), ih = fmaxf(iy1 - iy0, 0.f);
            float inter = iw * ih;
            float pa = (q2 - q0) * (q3 - q1);
            float ta = (t2 - t0) * (t3 - t1);
            float uni = pa + ta - inter;
            float iou = inter / (uni + EPS7);
            float e0 = fminf(q0, t0), e1 = fminf(q1, t1);
            float e2 = fmaxf(q2, t2), e3 = fmaxf(q3, t3);
            float ewd = fmaxf(e2 - e0, 0.f), ehd = fmaxf(e3 - e1, 0.f);
            float encl = ewd * ehd;
            float giou = iou - (encl - uni) / (encl + EPS7);
            acc += (double)(1.f - giou);
        }
    }

    for (int o = 32; o > 0; o >>= 1) {
        acc += __shfl_down(acc, o, 64);
        cnt_pos += __shfl_down(cnt_pos, o, 64);
    }
    int w = t >> 6, lane = t & 63;
    if (lane == 0) { sv[w] = acc; sc[w] = cnt_pos; }
    __syncthreads();
    if (t == 0) {
        int slot = blockIdx.y * gridDim.x + blockIdx.x;
        partS[slot] = sv[0] + sv[1] + sv[2] + sv[3];
        partC[slot] = sc[0] + sc[1] + sc[2] + sc[3];
    }
}

__global__ __launch_bounds__(256)
void final_kernel(const double* __restrict__ partS,
                  const int*    __restrict__ partC,
                  float* __restrict__ out, int n)
{
    __shared__ double sv[4];
    __shared__ long long sc[4];
    const int t = threadIdx.x;
    double a = 0.0; long long c = 0;
    for (int i = t; i < n; i += 256) { a += partS[i]; c += partC[i]; }
    for (int o = 32; o > 0; o >>= 1) {
        a += __shfl_down(a, o, 64);
        c += __shfl_down(c, o, 64);
    }
    int w = t >> 6, lane = t & 63;
    if (lane == 0) { sv[w] = a; sc[w] = c; }
    __syncthreads();
    if (t == 0) {
        double s = sv[0] + sv[1] + sv[2] + sv[3];
        long long np = sc[0] + sc[1] + sc[2] + sc[3];
        out[0] = (np == 0) ? 0.0f : (float)(s / (double)np);
    }
}

// ---------------------------------------------------------------------------
extern "C" void kernel_launch(void* const* d_in, const int* in_sizes, int n_in,
                              void* d_out, int out_size, void* d_ws, size_t ws_size,
                              hipStream_t stream)
{
    const float* locp = (const float*)d_in[0];   // [B,P,4]
    const float* conf = (const float*)d_in[1];   // [B,P,C]
    const float* dbox = (const float*)d_in[2];   // [P,4]
    const float* gt   = (const float*)d_in[3];   // [B,M,4]
    const int*   gtl  = (const int*)d_in[4];     // [B,M]

    const int P  = in_sizes[2] / 4;
    const long long BP = (long long)in_sizes[0] / 4;
    const int B  = (int)(BP / P);
    const int M  = in_sizes[4] / B;

    const int nblk = (P + 255) / 256;
    const int nPart = nblk * B;

    // ws layout (desc. alignment):
    // sbox[P] f4 | bpkey[B*M] u64 | partS f64 | hist i32 | offs i32 | sperm i32 | partC i32 | match u8
    char* ws = (char*)d_ws;
    size_t off = 0;
    float4* sbox = (float4*)(ws + off);           off += (size_t)P * 16;
    unsigned long long* bpkey = (unsigned long long*)(ws + off); off += (size_t)B * M * 8;
    double* partS = (double*)(ws + off);          off += (size_t)nPart * 8;
    int* hist  = (int*)(ws + off);                off += (size_t)NBUCK * 4;
    int* offs  = (int*)(ws + off);                off += (size_t)NBUCK * 4;
    int* sperm = (int*)(ws + off);                off += (size_t)P * 4;
    int* partC = (int*)(ws + off);                off += (size_t)nPart * 4;
    unsigned char* match = (unsigned char*)(ws + off);

    hipMemsetAsync(hist, 0, NBUCK * 4, stream);

    dim3 grid(nblk, B);
    histo_kernel<<<nblk, 256, 0, stream>>>((const float4*)dbox, hist, bpkey, P, B * M);
    scan_kernel<<<1, NBUCK, 0, stream>>>(hist, offs);
    scatter_kernel<<<nblk, 256, 0, stream>>>((const float4*)dbox, offs, sbox, sperm, P);
    match_kernel<<<grid, 256, 0, stream>>>(sbox, sperm, (const float4*)gt,
                                           bpkey, match, P, M);
    force_kernel<<<B, 64, 0, stream>>>(bpkey, match, P, M);
    loss_kernel<<<grid, 256, 0, stream>>>((const float4*)locp, conf,
                                          (const float4*)dbox, (const float4*)gt,
                                          gtl, match, partS, partC, P, M);
    final_kernel<<<1, 256, 0, stream>>>(partS, partC, (float*)d_out, nPart);
}